// Round 10
// baseline (23.836 us; speedup 1.0000x reference)
//
#include <hip/hip_runtime.h>
#include <math.h>

#define NQ   10
#define NL   4
#define NREG 16   // 1024 amplitudes / 64 lanes

typedef float f32x2 __attribute__((ext_vector_type(2)));

// ---------------------------------------------------------------------------
// Compile-time GF(2) tracking of the CNOT rings.
// stored[q] = amp[L q]; gate on logical bit p pairs {q, q^m}, m = col p of
// L^-1; logical bit value = parity(row_p(L) & q). Layer 0 folded into init.
// Layer-3 gates commuting with <Z> (parity(sgn&m)==0) are deleted.
// ---------------------------------------------------------------------------
struct MaskTab { int m[NL * NQ]; int d[NL * NQ]; bool keep[NL * NQ]; int sgn; bool ok; };

constexpr MaskTab make_masks() {
    MaskTab t{};
    int L[NQ] = {}, Li[NQ] = {};
    for (int p = 0; p < NQ; ++p) { L[p] = 1 << p; Li[p] = 1 << p; }
    for (int l = 0; l < NL; ++l) {
        for (int w = 0; w < NQ; ++w) {
            int p = NQ - 1 - w;
            int mm = 0;
            for (int tt = 0; tt < NQ; ++tt) mm |= ((Li[tt] >> p) & 1) << tt;
            t.m[l * NQ + w] = mm;
            t.d[l * NQ + w] = L[p];
        }
        int r = (l % (NQ - 1)) + 1;
        for (int w = 0; w < NQ; ++w) {           // L <- P_l^-1 L
            int pc = NQ - 1 - w;
            int tq = w + r; if (tq >= NQ) tq -= NQ;
            int pt = NQ - 1 - tq;
            L[pt] ^= L[pc];
        }
        for (int w = 0; w < NQ; ++w) {           // Li <- Li P_l
            int pc = NQ - 1 - w;
            int tq = w + r; if (tq >= NQ) tq -= NQ;
            int pt = NQ - 1 - tq;
            for (int p = 0; p < NQ; ++p)
                Li[p] ^= ((Li[p] >> pt) & 1) << pc;
        }
    }
    t.sgn = L[0];
    for (int gi = 0; gi < NL * NQ; ++gi) {
        if (gi < NQ) { t.keep[gi] = false; continue; }            // layer 0 folded
        if (gi < (NL - 1) * NQ) { t.keep[gi] = true; continue; }
        t.keep[gi] = (__builtin_popcount((unsigned)(t.sgn & t.m[gi])) & 1) != 0;
    }
    bool ok = true;
    for (int p = 0; p < NQ; ++p) {
        int row = 0;
        for (int k = 0; k < NQ; ++k)
            if ((L[p] >> k) & 1) row ^= Li[k];
        if (row != (1 << p)) ok = false;
    }
    t.ok = ok;
    return t;
}

static constexpr MaskTab MK = make_masks();
static_assert(MK.ok, "GF(2) inverse check failed");

// ---------------------------------------------------------------------------
// Cross-lane xor-exchange, routed by compile-time mask:
//   bits 0-3 only  -> 1-2 v_mov_dpp   (VALU pipe)
//   bits 0-4       -> 1 ds_swizzle    (DS pipe, xor BitMode)
//   bit 5 set      -> 1 ds_bpermute   (DS pipe, hoisted addr)
// ---------------------------------------------------------------------------
constexpr int dpp_direct(int m) {
    return m == 1 ? 0xB1 : m == 2 ? 0x4E : m == 3 ? 0x1B :
           m == 7 ? 0x141 : m == 8 ? 0x128 : m == 15 ? 0x140 : 0;
}
constexpr int dpp1(int m) {
    return dpp_direct(m)      ? dpp_direct(m) :
           dpp_direct(m ^ 8)  ? 0x128 :
           dpp_direct(m ^ 15) ? 0x140 : 0x141;
}
constexpr int dpp2(int m) {
    return dpp_direct(m)      ? 0 :
           dpp_direct(m ^ 8)  ? dpp_direct(m ^ 8) :
           dpp_direct(m ^ 15) ? dpp_direct(m ^ 15) : dpp_direct(m ^ 7);
}

template <int M>
__device__ __forceinline__ float xdpp(float v) {
    static_assert((M & ~15) == 0 && M != 0, "dpp mask must be 4-bit");
    int u = __builtin_amdgcn_mov_dpp(__float_as_int(v), dpp1(M), 0xF, 0xF, true);
    if constexpr (dpp2(M) != 0)
        u = __builtin_amdgcn_mov_dpp(u, dpp2(M), 0xF, 0xF, true);
    return __int_as_float(u);
}
template <int M>
__device__ __forceinline__ float xswz(float v) {
    static_assert((M & ~31) == 0 && M != 0, "swizzle mask must be 5-bit");
    return __int_as_float(__builtin_amdgcn_ds_swizzle(__float_as_int(v), (M << 10) | 0x1F));
}
__device__ __forceinline__ float xbp(int bpa, float v) {
    return __int_as_float(__builtin_amdgcn_ds_bpermute(bpa, __float_as_int(v)));
}

__device__ __forceinline__ float fxor(float a, unsigned s) {
    return __uint_as_float(__float_as_uint(a) ^ s);
}
__device__ __forceinline__ f32x2 bc2(float v) { f32x2 r; r.x = v; r.y = v; return r; }
__device__ __forceinline__ f32x2 cmul(f32x2 a, f32x2 b) {
    f32x2 r;
    r.x = a.x * b.x - a.y * b.y;
    r.y = a.x * b.y + a.y * b.x;
    return r;
}
__device__ __forceinline__ float rdl(float v, int l) {
    return __uint_as_float((unsigned)__builtin_amdgcn_readlane((int)__float_as_uint(v), l));
}

// ---------------------------------------------------------------------------
// Polynomial sincos (no library calls, no branches).
// sincos_tiny: |a| < ~0.5 (gate angles < 0.06): err < 2e-9.
// sincos_q:    a in [0, pi/2] (RX encoding): half-angle + deg-7/8, err ~3e-7.
// ---------------------------------------------------------------------------
__device__ __forceinline__ void sincos_tiny(float a, float* s, float* c) {
    float t = a * a;
    *s = a * fmaf(t, fmaf(t, 8.3333333e-3f, -0.16666667f), 1.0f);
    *c = fmaf(t, fmaf(t, fmaf(t, -1.3888889e-3f, 4.1666668e-2f), -0.5f), 1.0f);
}
__device__ __forceinline__ void sincos_q(float a, float* s, float* c) {
    float h = 0.5f * a, u = h * h;
    float sh = h * fmaf(u, fmaf(u, fmaf(u, -1.9841270e-4f, 8.3333333e-3f), -0.16666667f), 1.0f);
    float ch = fmaf(u, fmaf(u, fmaf(u, fmaf(u, 2.4801587e-5f, -1.3888889e-3f),
                                    4.1666668e-2f), -0.5f), 1.0f);
    *s = 2.0f * sh * ch;
    *c = fmaf(-2.0f * sh, sh, 1.0f);
}

// n = sc*s + pc*p with sc=(g00x, scy), pc=(pcx, g01y) sign-prefixed
// (Rot structure: g11 = conj(g00), g10 = -conj(g01)).
__device__ __forceinline__ f32x2 cmul2v(f32x2 s, f32x2 p,
                                        float g00x, float scy, float pcx, float g01y) {
    f32x2 sswap; sswap.x = -s.y; sswap.y = s.x;
    f32x2 pswap; pswap.x = -p.y; pswap.y = p.x;
    f32x2 n = s * bc2(g00x);
    n += sswap * bc2(scy);
    n += p * bc2(pcx);
    n += pswap * bc2(g01y);
    return n;
}

// ---------------------------------------------------------------------------
// One gate applied to TWO independent samples; coef broadcast, sign masks and
// lane parity are shared. Gathers for both issue before either compute, so the
// two dependency chains interleave.
// ---------------------------------------------------------------------------
template <int GI>
__device__ __forceinline__ void apply_gate2(f32x2 (&sA)[NREG], f32x2 (&sB)[NREG],
                                            float g00x_r, float g00y_r,
                                            float g01x_r, float g01y_r, int lane) {
    if constexpr (MK.keep[GI]) {
        constexpr int m     = MK.m[GI];
        constexpr int d     = MK.d[GI];
        constexpr int mreg  = (m >> 6) & 15;
        constexpr int mlane = m & 63;
        constexpr int dreg  = (d >> 6) & 15;
        constexpr int dlane = d & 63;
        constexpr bool useDPP = (mlane != 0) && ((mlane & 48) == 0);
        constexpr bool useSWZ = (mlane != 0) && !useDPP && ((mlane & 32) == 0);
        constexpr bool useBP  = (mlane != 0) && !useDPP && !useSWZ;

        const float g00x = rdl(g00x_r, GI);    // shared across both samples
        const float g00y = rdl(g00y_r, GI);
        const float g01x = rdl(g01x_r, GI);
        const float g01y = rdl(g01y_r, GI);

        const int bl = __popc(dlane & lane) & 1;
        const unsigned s0 = (unsigned)bl << 31;
        const float scy0 = fxor(g00y, s0), pcx0 = fxor(g01x, s0);
        const float scy1 = fxor(scy0, 0x80000000u), pcx1 = fxor(pcx0, 0x80000000u);

        [[maybe_unused]] int bpa = 0;
        if constexpr (useBP) bpa = (lane ^ mlane) << 2;   // hoisted, 1/gate

        // gather A then B: all exchange ops issue before the computes
        f32x2 ptA[NREG], ptB[NREG];
        #pragma unroll
        for (int j = 0; j < NREG; ++j) {
            f32x2 p = sA[j ^ mreg];
            if constexpr (useDPP) { p.x = xdpp<mlane & 15>(p.x); p.y = xdpp<mlane & 15>(p.y); }
            else if constexpr (useSWZ) { p.x = xswz<mlane & 31>(p.x); p.y = xswz<mlane & 31>(p.y); }
            else if constexpr (useBP)  { p.x = xbp(bpa, p.x); p.y = xbp(bpa, p.y); }
            ptA[j] = p;
        }
        #pragma unroll
        for (int j = 0; j < NREG; ++j) {
            f32x2 p = sB[j ^ mreg];
            if constexpr (useDPP) { p.x = xdpp<mlane & 15>(p.x); p.y = xdpp<mlane & 15>(p.y); }
            else if constexpr (useSWZ) { p.x = xswz<mlane & 31>(p.x); p.y = xswz<mlane & 31>(p.y); }
            else if constexpr (useBP)  { p.x = xbp(bpa, p.x); p.y = xbp(bpa, p.y); }
            ptB[j] = p;
        }
        // compute A, compute B: two independent FMA chains
        #pragma unroll
        for (int j = 0; j < NREG; ++j) {
            const int v = __popc(dreg & j) & 1;            // compile-time
            sA[j] = cmul2v(sA[j], ptA[j], g00x, v ? scy1 : scy0, v ? pcx1 : pcx0, g01y);
        }
        #pragma unroll
        for (int j = 0; j < NREG; ++j) {
            const int v = __popc(dreg & j) & 1;            // compile-time
            sB[j] = cmul2v(sB[j], ptB[j], g00x, v ? scy1 : scy0, v ? pcx1 : pcx0, g01y);
        }
    }
}

template <int GI>
__device__ __forceinline__ void gates_from2(f32x2 (&sA)[NREG], f32x2 (&sB)[NREG],
                                            float g00x_r, float g00y_r,
                                            float g01x_r, float g01y_r, int lane) {
    if constexpr (GI < NL * NQ) {
        apply_gate2<GI>(sA, sB, g00x_r, g00y_r, g01x_r, g01y_r, lane);
        gates_from2<GI + 1>(sA, sB, g00x_r, g00y_r, g01x_r, g01y_r, lane);
    }
}

// ---------------------------------------------------------------------------
// TWO samples per wave (independent ILP chains). States in 64 VGPRs.
// No LDS, no barriers, no lib calls.
// ---------------------------------------------------------------------------
__global__ __launch_bounds__(64) void qnn_kernel(const float* __restrict__ x,
                                                 const float* __restrict__ wts,
                                                 float* __restrict__ out) {
    const int b0   = blockIdx.x * 2;
    const int lane = threadIdx.x;

    // ---- gate coefficients: lane gi computes Rot gate gi (shared by both
    //      samples; branchless clamp for lanes >= 40).
    const int gidx = (lane < NL * NQ) ? lane : 0;
    float g00x_r, g00y_r, g01x_r, g01y_r;
    {
        float phi = wts[gidx * 3 + 0];
        float th  = wts[gidx * 3 + 1];
        float om  = wts[gidx * 3 + 2];
        float st_, ct_; sincos_tiny(0.5f * th, &st_, &ct_);
        float sp,  cp;  sincos_tiny(0.5f * (phi + om), &sp, &cp);
        float sm,  cm;  sincos_tiny(0.5f * (phi - om), &sm, &cm);
        g00x_r =  cp * ct_;  g00y_r = -sp * ct_;   // m00 = e^{-i(phi+om)/2} cos
        g01x_r = -cm * st_;  g01y_r = -sm * st_;   // m01 = -e^{+i(phi-om)/2} sin
    }

    // ---- RX encoding angles: lane s*10+w computes sincos(pi*x[b0+s][w]/2)
    float myc, mys;
    {
        const int sw = (lane < 2 * NQ) ? lane : 0;
        const int w  = (sw < NQ) ? sw : sw - NQ;
        const int sr = (sw < NQ) ? 0 : 1;
        sincos_q(1.57079632679f * x[(b0 + sr) * NQ + w], &mys, &myc);
    }

    // ---- per-sample init: fold layer-0 Rot into product factors, build state
    f32x2 stA[NREG], stB[NREG];
    #pragma unroll
    for (int s = 0; s < 2; ++s) {
        f32x2 u0[NQ], u1[NQ];
        #pragma unroll
        for (int w = 0; w < NQ; ++w) {
            const float a  = rdl(g00x_r, w), bb = rdl(g00y_r, w);
            const float c  = rdl(g01x_r, w), dd = rdl(g01y_r, w);
            const float cw = rdl(myc, s * NQ + w), sv = rdl(mys, s * NQ + w);
            const int p = NQ - 1 - w;
            u0[p].x =  a * cw + dd * sv;
            u0[p].y = bb * cw -  c * sv;
            u1[p].x = -c * cw - bb * sv;
            u1[p].y = dd * cw -  a * sv;
        }
        f32x2 PL = (lane & 1) ? u1[0] : u0[0];
        #pragma unroll
        for (int p = 1; p < 6; ++p)
            PL = cmul(PL, ((lane >> p) & 1) ? u1[p] : u0[p]);

        f32x2 t67[4], r89[4];
        #pragma unroll
        for (int a = 0; a < 4; ++a) {
            f32x2 r = cmul((a & 1) ? u1[6] : u0[6], (a & 2) ? u1[7] : u0[7]);
            t67[a] = cmul(PL, r);
            r89[a] = cmul((a & 1) ? u1[8] : u0[8], (a & 2) ? u1[9] : u0[9]);
        }
        #pragma unroll
        for (int j = 0; j < NREG; ++j) {
            f32x2 v = cmul(t67[j & 3], r89[j >> 2]);
            if (s == 0) stA[j] = v; else stB[j] = v;
        }
    }

    // ---- Rot gates (layers 1..3) on both samples; CNOT rings are free.
    gates_from2<NQ>(stA, stB, g00x_r, g00y_r, g01x_r, g01y_r, lane);

    // ---- <Z>: sign(q) = (-1)^parity(sgn & q), two reductions
    const int sl = __popc(MK.sgn & 63 & lane) & 1;
    const float bsign = sl ? -1.f : 1.f;
    float accA = 0.f, accB = 0.f;
    #pragma unroll
    for (int j = 0; j < NREG; ++j) {
        const int cj = __popc(((MK.sgn >> 6) & 15) & j) & 1;   // compile-time
        const float sgn = cj ? -bsign : bsign;
        accA = fmaf(fmaf(stA[j].x, stA[j].x, stA[j].y * stA[j].y), sgn, accA);
        accB = fmaf(fmaf(stB[j].x, stB[j].x, stB[j].y * stB[j].y), sgn, accB);
    }
    accA += xdpp<1>(accA);  accB += xdpp<1>(accB);
    accA += xdpp<2>(accA);  accB += xdpp<2>(accB);
    accA += xdpp<4>(accA);  accB += xdpp<4>(accB);
    accA += xdpp<8>(accA);  accB += xdpp<8>(accB);
    accA += xswz<16>(accA); accB += xswz<16>(accB);
    const int bpa32 = (lane ^ 32) << 2;
    accA += xbp(bpa32, accA);
    accB += xbp(bpa32, accB);
    if (lane == 0) { out[b0] = accA; out[b0 + 1] = accB; }
}

extern "C" void kernel_launch(void* const* d_in, const int* in_sizes, int n_in,
                              void* d_out, int out_size, void* d_ws, size_t ws_size,
                              hipStream_t stream) {
    (void)n_in; (void)d_ws; (void)ws_size; (void)out_size;
    const float* x   = (const float*)d_in[0];   // (2048, 10) float32
    const float* wts = (const float*)d_in[1];   // (4, 10, 3) float32
    float* out = (float*)d_out;                 // (2048, 1) float32
    int B = in_sizes[0] / NQ;                   // 2048
    qnn_kernel<<<B / 2, 64, 0, stream>>>(x, wts, out);
}

// Round 11
// 18.134 us; speedup vs baseline: 1.3144x; 1.3144x over previous
//
#include <hip/hip_runtime.h>
#include <math.h>

#define NQ   10
#define NL   4
#define NREG 16   // 1024 amplitudes / 64 lanes
#define NPK  8    // 8 f32x2 pairs (SoA packing of adjacent j)

typedef float f32x2 __attribute__((ext_vector_type(2)));

// ---------------------------------------------------------------------------
// Compile-time GF(2) tracking of the CNOT rings.
// stored[q] = amp[L q]; gate on logical bit p pairs {q, q^m}, m = col p of
// L^-1; logical bit value = parity(row_p(L) & q). Layer 0 folded into init.
// Layer-3 gates commuting with <Z> (parity(sgn&m)==0) are deleted.
// ---------------------------------------------------------------------------
struct MaskTab { int m[NL * NQ]; int d[NL * NQ]; bool keep[NL * NQ]; int sgn; bool ok; };

constexpr MaskTab make_masks() {
    MaskTab t{};
    int L[NQ] = {}, Li[NQ] = {};
    for (int p = 0; p < NQ; ++p) { L[p] = 1 << p; Li[p] = 1 << p; }
    for (int l = 0; l < NL; ++l) {
        for (int w = 0; w < NQ; ++w) {
            int p = NQ - 1 - w;
            int mm = 0;
            for (int tt = 0; tt < NQ; ++tt) mm |= ((Li[tt] >> p) & 1) << tt;
            t.m[l * NQ + w] = mm;
            t.d[l * NQ + w] = L[p];
        }
        int r = (l % (NQ - 1)) + 1;
        for (int w = 0; w < NQ; ++w) {           // L <- P_l^-1 L
            int pc = NQ - 1 - w;
            int tq = w + r; if (tq >= NQ) tq -= NQ;
            int pt = NQ - 1 - tq;
            L[pt] ^= L[pc];
        }
        for (int w = 0; w < NQ; ++w) {           // Li <- Li P_l
            int pc = NQ - 1 - w;
            int tq = w + r; if (tq >= NQ) tq -= NQ;
            int pt = NQ - 1 - tq;
            for (int p = 0; p < NQ; ++p)
                Li[p] ^= ((Li[p] >> pt) & 1) << pc;
        }
    }
    t.sgn = L[0];
    for (int gi = 0; gi < NL * NQ; ++gi) {
        if (gi < NQ) { t.keep[gi] = false; continue; }            // layer 0 folded
        if (gi < (NL - 1) * NQ) { t.keep[gi] = true; continue; }
        t.keep[gi] = (__builtin_popcount((unsigned)(t.sgn & t.m[gi])) & 1) != 0;
    }
    bool ok = true;
    for (int p = 0; p < NQ; ++p) {
        int row = 0;
        for (int k = 0; k < NQ; ++k)
            if ((L[p] >> k) & 1) row ^= Li[k];
        if (row != (1 << p)) ok = false;
    }
    t.ok = ok;
    return t;
}

static constexpr MaskTab MK = make_masks();
static_assert(MK.ok, "GF(2) inverse check failed");

// ---------------------------------------------------------------------------
// Cross-lane xor-exchange, routed by compile-time mask:
//   bits 0-3 only  -> 1-2 v_mov_dpp   (VALU pipe)
//   bits 0-4       -> 1 ds_swizzle    (DS pipe, xor BitMode)
//   bit 5 set      -> 1 ds_bpermute   (DS pipe, hoisted addr)
// ---------------------------------------------------------------------------
constexpr int dpp_direct(int m) {
    return m == 1 ? 0xB1 : m == 2 ? 0x4E : m == 3 ? 0x1B :
           m == 7 ? 0x141 : m == 8 ? 0x128 : m == 15 ? 0x140 : 0;
}
constexpr int dpp1(int m) {
    return dpp_direct(m)      ? dpp_direct(m) :
           dpp_direct(m ^ 8)  ? 0x128 :
           dpp_direct(m ^ 15) ? 0x140 : 0x141;
}
constexpr int dpp2(int m) {
    return dpp_direct(m)      ? 0 :
           dpp_direct(m ^ 8)  ? dpp_direct(m ^ 8) :
           dpp_direct(m ^ 15) ? dpp_direct(m ^ 15) : dpp_direct(m ^ 7);
}

template <int M>
__device__ __forceinline__ float xdpp(float v) {
    static_assert((M & ~15) == 0 && M != 0, "dpp mask must be 4-bit");
    int u = __builtin_amdgcn_mov_dpp(__float_as_int(v), dpp1(M), 0xF, 0xF, true);
    if constexpr (dpp2(M) != 0)
        u = __builtin_amdgcn_mov_dpp(u, dpp2(M), 0xF, 0xF, true);
    return __int_as_float(u);
}
template <int M>
__device__ __forceinline__ float xswz(float v) {
    static_assert((M & ~31) == 0 && M != 0, "swizzle mask must be 5-bit");
    return __int_as_float(__builtin_amdgcn_ds_swizzle(__float_as_int(v), (M << 10) | 0x1F));
}
__device__ __forceinline__ float xbp(int bpa, float v) {
    return __int_as_float(__builtin_amdgcn_ds_bpermute(bpa, __float_as_int(v)));
}

__device__ __forceinline__ float fxor(float a, unsigned s) {
    return __uint_as_float(__float_as_uint(a) ^ s);
}
__device__ __forceinline__ f32x2 bc2(float v) { f32x2 r; r.x = v; r.y = v; return r; }
__device__ __forceinline__ f32x2 swap2(f32x2 v) { f32x2 r; r.x = v.y; r.y = v.x; return r; }
__device__ __forceinline__ f32x2 cmul(f32x2 a, f32x2 b) {
    f32x2 r;
    r.x = a.x * b.x - a.y * b.y;
    r.y = a.x * b.y + a.y * b.x;
    return r;
}
__device__ __forceinline__ float rdl(float v, int l) {
    return __uint_as_float((unsigned)__builtin_amdgcn_readlane((int)__float_as_uint(v), l));
}

// ---------------------------------------------------------------------------
// Polynomial sincos (no library calls, no branches).
// sincos_tiny: |a| < ~0.5 (gate angles < 0.06): err < 2e-9.
// sincos_q:    a in [0, pi/2] (RX encoding): half-angle + deg-7/8, err ~3e-7.
// ---------------------------------------------------------------------------
__device__ __forceinline__ void sincos_tiny(float a, float* s, float* c) {
    float t = a * a;
    *s = a * fmaf(t, fmaf(t, 8.3333333e-3f, -0.16666667f), 1.0f);
    *c = fmaf(t, fmaf(t, fmaf(t, -1.3888889e-3f, 4.1666668e-2f), -0.5f), 1.0f);
}
__device__ __forceinline__ void sincos_q(float a, float* s, float* c) {
    float h = 0.5f * a, u = h * h;
    float sh = h * fmaf(u, fmaf(u, fmaf(u, -1.9841270e-4f, 8.3333333e-3f), -0.16666667f), 1.0f);
    float ch = fmaf(u, fmaf(u, fmaf(u, fmaf(u, 2.4801587e-5f, -1.3888889e-3f),
                                    4.1666668e-2f), -0.5f), 1.0f);
    *s = 2.0f * sh * ch;
    *c = fmaf(-2.0f * sh, sh, 1.0f);
}

// ---------------------------------------------------------------------------
// One gate on SoA state: X[k]/Y[k] hold re/im of amplitudes j=2k, 2k+1.
// The compute phase is pure element-wise vector FMA (v_pk_fma_f32-friendly):
//   nX = g00x*sX - scyv*sY + pcxv*pX - g01y*pY
//   nY = g00x*sY + scyv*sX + pcxv*pY + g01y*pX
// ---------------------------------------------------------------------------
template <int GI>
__device__ __forceinline__ void apply_gate(f32x2 (&X)[NPK], f32x2 (&Y)[NPK],
                                           float g00x_r, float g00y_r,
                                           float g01x_r, float g01y_r, int lane) {
    if constexpr (MK.keep[GI]) {
        constexpr int m     = MK.m[GI];
        constexpr int d     = MK.d[GI];
        constexpr int mreg  = (m >> 6) & 15;
        constexpr int mlane = m & 63;
        constexpr int dreg  = (d >> 6) & 15;
        constexpr int dlane = d & 63;
        constexpr int  kreg  = mreg >> 1;          // pair-index xor
        constexpr bool kswap = (mreg & 1) != 0;    // within-pair half swap
        constexpr bool useDPP = (mlane != 0) && ((mlane & 48) == 0);
        constexpr bool useSWZ = (mlane != 0) && !useDPP && ((mlane & 32) == 0);
        constexpr bool useBP  = (mlane != 0) && !useDPP && !useSWZ;

        const float g00x = rdl(g00x_r, GI);        // uniform broadcast, no DS
        const float g00y = rdl(g00y_r, GI);
        const float g01x = rdl(g01x_r, GI);
        const float g01y = rdl(g01y_r, GI);

        const int bl = __popc(dlane & lane) & 1;   // lane part of bit value
        const unsigned s0 = (unsigned)bl << 31;
        const float scy0 = fxor(g00y, s0), pcx0 = fxor(g01x, s0);
        const float scy1 = fxor(scy0, 0x80000000u), pcx1 = fxor(pcx0, 0x80000000u);

        // per-pair sign-vector variants (A: v(2k)=0, B: v(2k)=1)
        f32x2 scyA, scyB, pcxA, pcxB;
        if constexpr (dreg & 1) {                   // alternating within pair
            scyA.x = scy0; scyA.y = scy1;  scyB.x = scy1; scyB.y = scy0;
            pcxA.x = pcx0; pcxA.y = pcx1;  pcxB.x = pcx1; pcxB.y = pcx0;
        } else {                                    // uniform within pair
            scyA = bc2(scy0); scyB = bc2(scy1);
            pcxA = bc2(pcx0); pcxB = bc2(pcx1);
        }
        const f32x2 g00xv = bc2(g00x);
        const f32x2 g01yv = bc2(g01y);

        [[maybe_unused]] int bpa = 0;
        if constexpr (useBP) bpa = (lane ^ mlane) << 2;   // hoisted, 1/gate

        // gather phase: partner values for every pair
        f32x2 pX[NPK], pY[NPK];
        #pragma unroll
        for (int k = 0; k < NPK; ++k) {
            f32x2 px = X[k ^ kreg], py = Y[k ^ kreg];
            if constexpr (kswap) { px = swap2(px); py = swap2(py); }
            if constexpr (useDPP) {
                px.x = xdpp<mlane & 15>(px.x); px.y = xdpp<mlane & 15>(px.y);
                py.x = xdpp<mlane & 15>(py.x); py.y = xdpp<mlane & 15>(py.y);
            } else if constexpr (useSWZ) {
                px.x = xswz<mlane & 31>(px.x); px.y = xswz<mlane & 31>(px.y);
                py.x = xswz<mlane & 31>(py.x); py.y = xswz<mlane & 31>(py.y);
            } else if constexpr (useBP) {
                px.x = xbp(bpa, px.x); px.y = xbp(bpa, px.y);
                py.x = xbp(bpa, py.x); py.y = xbp(bpa, py.y);
            }
            pX[k] = px; pY[k] = py;
        }
        // compute phase: element-wise vector FMA only
        #pragma unroll
        for (int k = 0; k < NPK; ++k) {
            const int vs = __popc(dreg & (2 * k)) & 1;     // compile-time
            const f32x2 scyv = vs ? scyB : scyA;
            const f32x2 pcxv = vs ? pcxB : pcxA;
            const f32x2 sX = X[k], sY = Y[k];
            f32x2 nX = sX * g00xv;
            nX -= scyv * sY;
            nX += pcxv * pX[k];
            nX -= g01yv * pY[k];
            f32x2 nY = sY * g00xv;
            nY += scyv * sX;
            nY += pcxv * pY[k];
            nY += g01yv * pX[k];
            X[k] = nX; Y[k] = nY;
        }
    }
}

template <int GI>
__device__ __forceinline__ void gates_from(f32x2 (&X)[NPK], f32x2 (&Y)[NPK],
                                           float g00x_r, float g00y_r,
                                           float g01x_r, float g01y_r, int lane) {
    if constexpr (GI < NL * NQ) {
        apply_gate<GI>(X, Y, g00x_r, g00y_r, g01x_r, g01y_r, lane);
        gates_from<GI + 1>(X, Y, g00x_r, g00y_r, g01x_r, g01y_r, lane);
    }
}

// ---------------------------------------------------------------------------
// One sample per wave. SoA state in 32 VGPRs. No LDS, no barriers, no libcalls.
// ---------------------------------------------------------------------------
__global__ __launch_bounds__(64) void qnn_kernel(const float* __restrict__ x,
                                                 const float* __restrict__ wts,
                                                 float* __restrict__ out) {
    const int b    = blockIdx.x;
    const int lane = threadIdx.x;

    // ---- gate coefficients: lane gi computes Rot gate gi (branchless clamp)
    const int gidx = (lane < NL * NQ) ? lane : 0;
    float g00x_r, g00y_r, g01x_r, g01y_r;
    {
        float phi = wts[gidx * 3 + 0];
        float th  = wts[gidx * 3 + 1];
        float om  = wts[gidx * 3 + 2];
        float st_, ct_; sincos_tiny(0.5f * th, &st_, &ct_);
        float sp,  cp;  sincos_tiny(0.5f * (phi + om), &sp, &cp);
        float sm,  cm;  sincos_tiny(0.5f * (phi - om), &sm, &cm);
        g00x_r =  cp * ct_;  g00y_r = -sp * ct_;   // m00 = e^{-i(phi+om)/2} cos
        g01x_r = -cm * st_;  g01y_r = -sm * st_;   // m01 = -e^{+i(phi-om)/2} sin
    }

    // ---- RX encoding angles: lane w computes sincos(pi*x_w/2), a in [0,pi/2]
    float myc, mys;
    {
        const int w = (lane < NQ) ? lane : 0;
        sincos_q(1.57079632679f * x[b * NQ + w], &mys, &myc);
    }

    // ---- fold layer-0 Rot into product factors, per-lane via readlane
    f32x2 u0[NQ], u1[NQ];
    #pragma unroll
    for (int w = 0; w < NQ; ++w) {
        const float a  = rdl(g00x_r, w), bb = rdl(g00y_r, w);
        const float c  = rdl(g01x_r, w), dd = rdl(g01y_r, w);
        const float cw = rdl(myc, w),    sw = rdl(mys, w);
        const int p = NQ - 1 - w;
        u0[p].x =  a * cw + dd * sw;
        u0[p].y = bb * cw -  c * sw;
        u1[p].x = -c * cw - bb * sw;
        u1[p].y = dd * cw -  a * sw;
    }

    // ---- init: product state  a[q] = prod_p u'_{p, bit_p(q)}, packed SoA
    f32x2 PL = (lane & 1) ? u1[0] : u0[0];
    #pragma unroll
    for (int p = 1; p < 6; ++p)
        PL = cmul(PL, ((lane >> p) & 1) ? u1[p] : u0[p]);

    f32x2 t67[4], r89[4];
    #pragma unroll
    for (int a = 0; a < 4; ++a) {
        f32x2 r = cmul((a & 1) ? u1[6] : u0[6], (a & 2) ? u1[7] : u0[7]);
        t67[a] = cmul(PL, r);
        r89[a] = cmul((a & 1) ? u1[8] : u0[8], (a & 2) ? u1[9] : u0[9]);
    }

    f32x2 X[NPK], Y[NPK];
    #pragma unroll
    for (int k = 0; k < NPK; ++k) {
        const int j0 = 2 * k, j1 = 2 * k + 1;
        f32x2 a0 = cmul(t67[j0 & 3], r89[j0 >> 2]);
        f32x2 a1 = cmul(t67[j1 & 3], r89[j1 >> 2]);
        X[k].x = a0.x; X[k].y = a1.x;
        Y[k].x = a0.y; Y[k].y = a1.y;
    }

    // ---- Rot gates (layers 1..3) in stored space; CNOT rings are free.
    gates_from<NQ>(X, Y, g00x_r, g00y_r, g01x_r, g01y_r, lane);

    // ---- <Z>: sign(q) = (-1)^parity(sgn & q)
    const int sl = __popc(MK.sgn & 63 & lane) & 1;
    const float bsign = sl ? -1.f : 1.f;
    const int sb = (MK.sgn >> 6) & 15;
    float acc = 0.f;
    #pragma unroll
    for (int k = 0; k < NPK; ++k) {
        const int c0 = __popc(sb & (2 * k)) & 1;           // compile-time
        const int c1 = c0 ^ (sb & 1);
        f32x2 mag = X[k] * X[k] + Y[k] * Y[k];
        acc = fmaf(mag.x, c0 ? -bsign : bsign, acc);
        acc = fmaf(mag.y, c1 ? -bsign : bsign, acc);
    }
    // ---- wave reduction: DPP for 1,2,4,8; swizzle for 16; bpermute for 32
    acc += xdpp<1>(acc);
    acc += xdpp<2>(acc);
    acc += xdpp<4>(acc);
    acc += xdpp<8>(acc);
    acc += xswz<16>(acc);
    acc += xbp((lane ^ 32) << 2, acc);
    if (lane == 0) out[b] = acc;
}

extern "C" void kernel_launch(void* const* d_in, const int* in_sizes, int n_in,
                              void* d_out, int out_size, void* d_ws, size_t ws_size,
                              hipStream_t stream) {
    (void)n_in; (void)d_ws; (void)ws_size; (void)out_size;
    const float* x   = (const float*)d_in[0];   // (2048, 10) float32
    const float* wts = (const float*)d_in[1];   // (4, 10, 3) float32
    float* out = (float*)d_out;                 // (2048, 1) float32
    int B = in_sizes[0] / NQ;                   // 2048
    qnn_kernel<<<B, 64, 0, stream>>>(x, wts, out);
}